// Round 11
// baseline (140.459 us; speedup 1.0000x reference)
//
#include <hip/hip_runtime.h>

#define NEGV -1e30f

// Problem constants (fixed by setup_inputs)
constexpr int Bn = 8, Ci = 64, Hn = 64, Wn = 64, Co = 64;
constexpr int WT_ELEMS = Ci * 9 * Co;   // 36864
constexpr int HW = Hn * Wn;

typedef float v2f __attribute__((ext_vector_type(2)));

// ---- pre-pass: wT[ci][k][co] = wt[co][ci][k] (147456 B in d_ws) ----
__global__ __launch_bounds__(256)
void wtrans_kernel(const float* __restrict__ wt, float* __restrict__ wT) {
    int idx = blockIdx.x * 256 + threadIdx.x;
    if (idx < WT_ELEMS) {
        int co = idx & 63;
        int k  = (idx >> 6) % 9;
        int ci = idx / 576;
        wT[idx] = wt[((size_t)co * Ci + ci) * 9 + k];
    }
}

__device__ __forceinline__ float vmax3(float a, float b, float c) {
    float d;
    asm("v_max3_f32 %0, %1, %2, %3" : "=v"(d) : "v"(a), "v"(b), "v"(c));
    return d;
}

// uniform LDS window read: 10 floats as 5 even-aligned v2f
// (b128 -> r[0],r[1]; b128 -> r[2],r[3]; b64 -> r[4])
__device__ __forceinline__ void read10v(v2f* r, const float* __restrict__ p) {
    float4 a = *reinterpret_cast<const float4*>(p);
    float4 b = *reinterpret_cast<const float4*>(p + 4);
    float2 c = *reinterpret_cast<const float2*>(p + 8);
    r[0] = (v2f){a.x, a.y}; r[1] = (v2f){a.z, a.w};
    r[2] = (v2f){b.x, b.y}; r[3] = (v2f){b.z, b.w};
    r[4] = (v2f){c.x, c.y};
}

// Packed core: per pixel PAIR per row: 2 v_pk_add_f32 + 2 v_add (middle col),
// then 5 max ops per px (3-ary reduction floor). 88 VALU/ci/wave vs 112.
__device__ __forceinline__ void compute8pk(float* acc, const v2f* xu,
                                           const v2f* xc, const v2f* xd,
                                           const float* wv) {
    const v2f w0 = {wv[0], wv[0]}, w2 = {wv[2], wv[2]};
    const v2f w3 = {wv[3], wv[3]}, w5 = {wv[5], wv[5]};
    const v2f w6 = {wv[6], wv[6]}, w8 = {wv[8], wv[8]};
#pragma unroll
    for (int q = 0; q < 4; q++) {
        v2f u0 = xu[q] + w0, u2 = xu[q + 1] + w2;       // pk_add
        float u1a = xu[q].y + wv[1], u1b = xu[q + 1].x + wv[1];
        v2f c0 = xc[q] + w3, c2 = xc[q + 1] + w5;
        float c1a = xc[q].y + wv[4], c1b = xc[q + 1].x + wv[4];
        v2f d0 = xd[q] + w6, d2 = xd[q + 1] + w8;
        float d1a = xd[q].y + wv[7], d1b = xd[q + 1].x + wv[7];
        // pixel 2q
        float m0 = vmax3(u0.x, u1a, u2.x);
        float m1 = vmax3(c0.x, c1a, c2.x);
        float m2 = vmax3(d0.x, d1a, d2.x);
        float a0 = vmax3(acc[2 * q], m0, m1);
        acc[2 * q] = fmaxf(a0, m2);
        // pixel 2q+1
        float n0 = vmax3(u0.y, u1b, u2.y);
        float n1 = vmax3(c0.y, c1b, c2.y);
        float n2 = vmax3(d0.y, d1b, d2.y);
        float a1 = vmax3(acc[2 * q + 1], n0, n1);
        acc[2 * q + 1] = fmaxf(a1, n2);
    }
}

// R8 structure (best measured): lane = co, wave = 8 px of one row, block =
// (b, h, half-row) = 4 waves; x staged in LDS once (no loop barriers);
// weights coalesced VMEM; compiler-scheduled loop (R10's explicit ping-pong
// regressed: VGPR couldn't hold 2 sets -> rotation movs). Only change vs R8:
// packed-add core (-21% VALU instrs) to test the issue-bound theory.
__global__ __launch_bounds__(256, 4)
void maxconv_main(const float* __restrict__ x, const float* __restrict__ wT,
                  float* __restrict__ out) {
    __shared__ __align__(16) float xs[Ci * 120];   // [ci][3 rows][40] = 30720 B

    const int tid  = threadIdx.x;
    const int lane = tid & 63;
    const int wvid = tid >> 6;                      // 0..3

    // XCD chunking: hw id%8 selects XCD; logical chunk = one batch image b.
    const int lg   = ((blockIdx.x & 7) << 7) | (blockIdx.x >> 3);
    const int b    = lg >> 7;
    const int rem  = lg & 127;
    const int h    = rem >> 1;
    const int half = rem & 1;
    const int w0h  = half << 5;                     // 0 or 32

    // ---- upfront staging (identical to R8, verified): threads {0..101} do
    // ci 0..31, {128..229} ci 32..63; invalid coords write NEGV.
    {
        const int st     = (tid < 128) ? tid : tid - 128;
        const int cibase = (tid < 128) ? 0 : 32;
        if (st < 102) {
            const int r    = st / 34;
            const int s    = st - r * 34;
            const int grow = h - 1 + r;
            const int gcol = w0h - 1 + s;
            const bool valid = (grow >= 0) && (grow < Hn) && (gcol >= 0) && (gcol < Wn);
            const int cg   = valid ? grow : 0;
            const int cc   = valid ? gcol : 0;
            const float* gp = x + (((size_t)b * Ci + cibase) * Hn + cg) * Wn + cc;
            const int dst  = r * 40 + s;
#pragma unroll 1
            for (int c8 = 0; c8 < 32; c8 += 8) {
                float v[8];
#pragma unroll
                for (int i = 0; i < 8; i++)
                    v[i] = valid ? gp[(size_t)(c8 + i) * HW] : NEGV;
#pragma unroll
                for (int i = 0; i < 8; i++)
                    xs[(cibase + c8 + i) * 120 + dst] = v[i];
            }
        }
    }
    __syncthreads();   // the only block-wide sync

    const int woff = wvid * 8;          // this wave's slot base (16B-aligned)

    const float* wq = wT + lane;        // weight stream
    const float* xq = xs + woff;        // LDS stream

    float acc[8];
#pragma unroll
    for (int j = 0; j < 8; j++) acc[j] = NEGV;

#pragma unroll 1
    for (int ci = 0; ci < Ci; ci += 2) {
        // ---- ci ----
        float wv[9];
#pragma unroll
        for (int k = 0; k < 9; k++) wv[k] = wq[k * 64];   // coalesced, imm offs
        v2f xu[5], xc[5], xd[5];
        read10v(xu, xq); read10v(xc, xq + 40); read10v(xd, xq + 80);
        compute8pk(acc, xu, xc, xd, wv);
        wq += 576; xq += 120;

        // ---- ci+1 ----
        float wv2[9];
#pragma unroll
        for (int k = 0; k < 9; k++) wv2[k] = wq[k * 64];
        v2f yu[5], yc[5], yd[5];
        read10v(yu, xq); read10v(yc, xq + 40); read10v(yd, xq + 80);
        compute8pk(acc, yu, yc, yd, wv2);
        wq += 576; xq += 120;
    }

    // lane holds 8 consecutive px of its co plane -> two dwordx4 stores
    float* po = out + (((size_t)b * Co + lane) * Hn + h) * Wn + w0h + woff;
    *reinterpret_cast<float4*>(po)     = make_float4(acc[0], acc[1], acc[2], acc[3]);
    *reinterpret_cast<float4*>(po + 4) = make_float4(acc[4], acc[5], acc[6], acc[7]);
}

extern "C" void kernel_launch(void* const* d_in, const int* in_sizes, int n_in,
                              void* d_out, int out_size, void* d_ws, size_t ws_size,
                              hipStream_t stream) {
    const float* x  = (const float*)d_in[0];
    const float* wt = (const float*)d_in[1];
    float* out = (float*)d_out;
    float* wT  = (float*)d_ws;   // 147456 B

    wtrans_kernel<<<(WT_ELEMS + 255) / 256, 256, 0, stream>>>(wt, wT);

    // 1024 blocks = 4 blocks/CU = 16 waves/CU; LDS 30 KB x 4 = 120 KB/CU
    maxconv_main<<<1024, 256, 0, stream>>>(x, wT, out);
}

// Round 12
// 113.166 us; speedup vs baseline: 1.2412x; 1.2412x over previous
//
#include <hip/hip_runtime.h>

#define NEGV -1e30f

// Problem constants (fixed by setup_inputs)
constexpr int Bn = 8, Ci = 64, Hn = 64, Wn = 64, Co = 64;
constexpr int WT_ELEMS = Ci * 9 * Co;   // 36864
constexpr int HW = Hn * Wn;

// ---- pre-pass: wT[ci][k][co] = wt[co][ci][k] (147456 B in d_ws) ----
__global__ __launch_bounds__(256)
void wtrans_kernel(const float* __restrict__ wt, float* __restrict__ wT) {
    int idx = blockIdx.x * 256 + threadIdx.x;
    if (idx < WT_ELEMS) {
        int co = idx & 63;
        int k  = (idx >> 6) % 9;
        int ci = idx / 576;
        wT[idx] = wt[((size_t)co * Ci + ci) * 9 + k];
    }
}

__device__ __forceinline__ float vmax3(float a, float b, float c) {
    float d;
    asm("v_max3_f32 %0, %1, %2, %3" : "=v"(d) : "v"(a), "v"(b), "v"(c));
    return d;
}

// uniform LDS window read: 10 floats = b128 + b128 + b64 (16B-aligned base)
__device__ __forceinline__ void read10(float* o, const float* __restrict__ p) {
    float4 a = *reinterpret_cast<const float4*>(p);
    float4 b = *reinterpret_cast<const float4*>(p + 4);
    float2 c = *reinterpret_cast<const float2*>(p + 8);
    o[0] = a.x; o[1] = a.y; o[2] = a.z; o[3] = a.w;
    o[4] = b.x; o[5] = b.y; o[6] = b.z; o[7] = b.w;
    o[8] = c.x; o[9] = c.y;
}

// pure core: per px 9 v_add + 4 v_max3 + 1 v_max (R8-verified scalar form —
// R11's v2f packing spilled to scratch and regressed)
__device__ __forceinline__ void compute8(float* acc, const float* xu,
                                         const float* xc, const float* xd,
                                         const float* wv) {
#pragma unroll
    for (int j = 0; j < 8; j++) {
        float t0 = xu[j] + wv[0], t1 = xu[j + 1] + wv[1], t2 = xu[j + 2] + wv[2];
        float t3 = xc[j] + wv[3], t4 = xc[j + 1] + wv[4], t5 = xc[j + 2] + wv[5];
        float t6 = xd[j] + wv[6], t7 = xd[j + 1] + wv[7], t8 = xd[j + 2] + wv[8];
        float m0 = vmax3(t0, t1, t2);
        float m1 = vmax3(t3, t4, t5);
        float m2 = vmax3(t6, t7, t8);
        acc[j] = vmax3(acc[j], m0, m1);
        acc[j] = fmaxf(acc[j], m2);
    }
}

// R8 structure with ci-SPLIT waves: block = 512 threads = 8 waves covering
// (b, h, half-row of 32 px); wave = (px-quad, ci-half). Identical total VALU /
// LDS / VMEM instruction counts to R8, but 8 waves/SIMD instead of 4 ->
// natural-lockstep stalls (LDS-read bursts vs compute) can cross-fill.
// Halves combine at the end via an LDS exchange + fmax (trivial one-time).
__global__ __launch_bounds__(512, 8)
void maxconv_main(const float* __restrict__ x, const float* __restrict__ wT,
                  float* __restrict__ out) {
    __shared__ __align__(16) float xs[Ci * 120];   // [ci][3 rows][40] = 30720 B

    const int tid  = threadIdx.x;
    const int lane = tid & 63;
    const int wid  = tid >> 6;                      // 0..7

    // XCD chunking: hw id%8 selects XCD; logical chunk = one batch image b.
    const int lg   = ((blockIdx.x & 7) << 7) | (blockIdx.x >> 3);
    const int b    = lg >> 7;
    const int rem  = lg & 127;
    const int h    = rem >> 1;
    const int half = rem & 1;
    const int w0h  = half << 5;                     // 0 or 32

    // ---- upfront staging: quarter q = tid>>7 stages ci q*16..q*16+15;
    // within a quarter, threads st<102 own one (row r, slot s). Invalid
    // coords write NEGV (borders handled for free).
    {
        const int q      = tid >> 7;                // 0..3
        const int st     = tid & 127;
        const int cibase = q * 16;
        if (st < 102) {
            const int r    = st / 34;
            const int s    = st - r * 34;
            const int grow = h - 1 + r;
            const int gcol = w0h - 1 + s;
            const bool valid = (grow >= 0) && (grow < Hn) && (gcol >= 0) && (gcol < Wn);
            const int cg   = valid ? grow : 0;
            const int cc   = valid ? gcol : 0;
            const float* gp = x + (((size_t)b * Ci + cibase) * Hn + cg) * Wn + cc;
            const int dst  = r * 40 + s;
#pragma unroll 1
            for (int c8 = 0; c8 < 16; c8 += 8) {
                float v[8];
#pragma unroll
                for (int i = 0; i < 8; i++)
                    v[i] = valid ? gp[(size_t)(c8 + i) * HW] : NEGV;
#pragma unroll
                for (int i = 0; i < 8; i++)
                    xs[(cibase + c8 + i) * 120 + dst] = v[i];
            }
        }
    }
    __syncthreads();

    const int quad   = wid >> 1;        // px-quad 0..3 (8 px each)
    const int cihalf = wid & 1;         // 0: ci 0..31, 1: ci 32..63
    const int woff   = quad * 8;        // slot base (16B-aligned)

    const float* wq = wT + (size_t)cihalf * 32 * 576 + lane;
    const float* xq = xs + cihalf * 32 * 120 + woff;

    float acc[8];
#pragma unroll
    for (int j = 0; j < 8; j++) acc[j] = NEGV;

#pragma unroll 1
    for (int ci = 0; ci < 32; ci += 2) {
        // ---- first ci ----
        float wv[9];
#pragma unroll
        for (int k = 0; k < 9; k++) wv[k] = wq[k * 64];   // coalesced, imm offs
        float xu[10], xc[10], xd[10];
        read10(xu, xq); read10(xc, xq + 40); read10(xd, xq + 80);
        compute8(acc, xu, xc, xd, wv);
        wq += 576; xq += 120;

        // ---- second ci ----
        float wv2[9];
#pragma unroll
        for (int k = 0; k < 9; k++) wv2[k] = wq[k * 64];
        float yu[10], yc[10], yd[10];
        read10(yu, xq); read10(yc, xq + 40); read10(yd, xq + 80);
        compute8(acc, yu, yc, yd, wv2);
        wq += 576; xq += 120;
    }

    // ---- combine ci-halves: half-1 waves park acc in xs (now dead), half-0
    // waves fmax and store. One-time cost.
    __syncthreads();
    if (cihalf) {
        float* ps = xs + quad * 512 + lane * 8;
        *reinterpret_cast<float4*>(ps)     = make_float4(acc[0], acc[1], acc[2], acc[3]);
        *reinterpret_cast<float4*>(ps + 4) = make_float4(acc[4], acc[5], acc[6], acc[7]);
    }
    __syncthreads();
    if (!cihalf) {
        const float* ps = xs + quad * 512 + lane * 8;
        float4 o0 = *reinterpret_cast<const float4*>(ps);
        float4 o1 = *reinterpret_cast<const float4*>(ps + 4);
        acc[0] = fmaxf(acc[0], o0.x); acc[1] = fmaxf(acc[1], o0.y);
        acc[2] = fmaxf(acc[2], o0.z); acc[3] = fmaxf(acc[3], o0.w);
        acc[4] = fmaxf(acc[4], o1.x); acc[5] = fmaxf(acc[5], o1.y);
        acc[6] = fmaxf(acc[6], o1.z); acc[7] = fmaxf(acc[7], o1.w);

        float* po = out + (((size_t)b * Co + lane) * Hn + h) * Wn + w0h + woff;
        *reinterpret_cast<float4*>(po)     = make_float4(acc[0], acc[1], acc[2], acc[3]);
        *reinterpret_cast<float4*>(po + 4) = make_float4(acc[4], acc[5], acc[6], acc[7]);
    }
}

extern "C" void kernel_launch(void* const* d_in, const int* in_sizes, int n_in,
                              void* d_out, int out_size, void* d_ws, size_t ws_size,
                              hipStream_t stream) {
    const float* x  = (const float*)d_in[0];
    const float* wt = (const float*)d_in[1];
    float* out = (float*)d_out;
    float* wT  = (float*)d_ws;   // 147456 B

    wtrans_kernel<<<(WT_ELEMS + 255) / 256, 256, 0, stream>>>(wt, wT);

    // 1024 blocks x 512 threads = 4 blocks/CU = 32 waves/CU (8/SIMD);
    // LDS 30 KB x 4 = 120 KB/CU.
    maxconv_main<<<1024, 512, 0, stream>>>(x, wT, out);
}

// Round 14
// 111.600 us; speedup vs baseline: 1.2586x; 1.0140x over previous
//
#include <hip/hip_runtime.h>

#define NEGV -1e30f

// Problem constants (fixed by setup_inputs)
constexpr int Bn = 8, Ci = 64, Hn = 64, Wn = 64, Co = 64;
constexpr int WT_ELEMS = Ci * 9 * Co;   // 36864
constexpr int HW = Hn * Wn;

// ---- pre-pass: wT[ci][k][co] = wt[co][ci][k] (147456 B in d_ws) ----
__global__ __launch_bounds__(256)
void wtrans_kernel(const float* __restrict__ wt, float* __restrict__ wT) {
    int idx = blockIdx.x * 256 + threadIdx.x;
    if (idx < WT_ELEMS) {
        int co = idx & 63;
        int k  = (idx >> 6) % 9;
        int ci = idx / 576;
        wT[idx] = wt[((size_t)co * Ci + ci) * 9 + k];
    }
}

__device__ __forceinline__ float vmax3(float a, float b, float c) {
    float d;
    asm("v_max3_f32 %0, %1, %2, %3" : "=v"(d) : "v"(a), "v"(b), "v"(c));
    return d;
}

// uniform LDS window read: 10 floats = b128 + b128 + b64 (16B-aligned base)
__device__ __forceinline__ void read10(float* o, const float* __restrict__ p) {
    float4 a = *reinterpret_cast<const float4*>(p);
    float4 b = *reinterpret_cast<const float4*>(p + 4);
    float2 c = *reinterpret_cast<const float2*>(p + 8);
    o[0] = a.x; o[1] = a.y; o[2] = a.z; o[3] = a.w;
    o[4] = b.x; o[5] = b.y; o[6] = b.z; o[7] = b.w;
    o[8] = c.x; o[9] = c.y;
}

// pure core: per px 9 v_add + 4 v_max3 + 1 v_max
__device__ __forceinline__ void compute8(float* acc, const float* xu,
                                         const float* xc, const float* xd,
                                         const float* wv) {
#pragma unroll
    for (int j = 0; j < 8; j++) {
        float t0 = xu[j] + wv[0], t1 = xu[j + 1] + wv[1], t2 = xu[j + 2] + wv[2];
        float t3 = xc[j] + wv[3], t4 = xc[j + 1] + wv[4], t5 = xc[j + 2] + wv[5];
        float t6 = xd[j] + wv[6], t7 = xd[j + 1] + wv[7], t8 = xd[j + 2] + wv[8];
        float m0 = vmax3(t0, t1, t2);
        float m1 = vmax3(t3, t4, t5);
        float m2 = vmax3(t6, t7, t8);
        acc[j] = vmax3(acc[j], m0, m1);
        acc[j] = fmaxf(acc[j], m2);
    }
}

// LDS-pipe discriminator: wave computes TWO output rows (h0, h0+1) from FOUR
// staged rows (h0-1..h0+2). The 4 row-reads (12 ds instrs) serve 16 px
// (vs 9 ds for 8 px in R12): ds/px 1.125 -> 0.75, weight-VMEM/px halves,
// core VALU/px unchanged (loads shared, weights per out-row are not).
// Block = (b, row-pair, half-row of 32 cols): 512 thr = 8 waves =
// (px-quad x ci-half); LDS [ci][4 rows][40] = 40 KB; 512 blocks = 2/CU.
__global__ __launch_bounds__(512, 4)
void maxconv_main(const float* __restrict__ x, const float* __restrict__ wT,
                  float* __restrict__ out) {
    __shared__ __align__(16) float xs[Ci * 160];   // 40960 B

    const int tid  = threadIdx.x;
    const int lane = tid & 63;
    const int wid  = tid >> 6;                      // 0..7

    // XCD chunking: 512 blocks, 64 per XCD = exactly one batch image b.
    const int lg   = ((blockIdx.x & 7) << 6) | (blockIdx.x >> 3);
    const int b    = lg >> 6;
    const int rem  = lg & 63;
    const int pair = rem >> 1;
    const int half = rem & 1;
    const int h0   = pair * 2;
    const int w0h  = half << 5;                     // 0 or 32

    // ---- upfront staging: 544 units = (4 ci-quarters) x (4 rows x 34 slots);
    // unit stages 16 ci of one (row,slot). Invalid coords write NEGV.
    for (int u = tid; u < 544; u += 512) {
        const int ciq  = u / 136;
        const int r2   = u - ciq * 136;
        const int r    = r2 / 34;
        const int s    = r2 - r * 34;
        const int cibase = ciq * 16;
        const int grow = h0 - 1 + r;
        const int gcol = w0h - 1 + s;
        const bool valid = (grow >= 0) && (grow < Hn) && (gcol >= 0) && (gcol < Wn);
        const int cg   = valid ? grow : 0;
        const int cc   = valid ? gcol : 0;
        const float* gp = x + (((size_t)b * Ci + cibase) * Hn + cg) * Wn + cc;
        const int dst  = r * 40 + s;
#pragma unroll 1
        for (int c8 = 0; c8 < 16; c8 += 8) {
            float v[8];
#pragma unroll
            for (int i = 0; i < 8; i++)
                v[i] = valid ? gp[(size_t)(c8 + i) * HW] : NEGV;
#pragma unroll
            for (int i = 0; i < 8; i++)
                xs[(cibase + c8 + i) * 160 + dst] = v[i];
        }
    }
    __syncthreads();

    const int quad   = wid >> 1;        // px-quad 0..3 (8 cols each)
    const int cihalf = wid & 1;         // 0: ci 0..31, 1: ci 32..63
    const int woff   = quad * 8;        // slot base (16B-aligned)

    const float* wq = wT + (size_t)cihalf * 32 * 576 + lane;
    const float* xq = xs + cihalf * 32 * 160 + woff;

    float acc0[8], acc1[8];
#pragma unroll
    for (int j = 0; j < 8; j++) { acc0[j] = NEGV; acc1[j] = NEGV; }

#pragma unroll 1
    for (int ci = 0; ci < 32; ci++) {
        float wv[9];
#pragma unroll
        for (int k = 0; k < 9; k++) wv[k] = wq[k * 64];   // coalesced, imm offs
        float r0[10], r1[10], r2[10], r3[10];
        read10(r0, xq);       read10(r1, xq + 40);
        read10(r2, xq + 80);  read10(r3, xq + 120);
        compute8(acc0, r0, r1, r2, wv);    // out-row h0   (rows h0-1,h0,h0+1)
        compute8(acc1, r1, r2, r3, wv);    // out-row h0+1 (rows h0,h0+1,h0+2)
        wq += 576; xq += 160;
    }

    // ---- combine ci-halves via xs (dead after loop): half-1 parks, half-0
    // maxes and stores both rows.
    __syncthreads();
    if (cihalf) {
        float* ps = xs + quad * 1024 + lane * 16;
        *reinterpret_cast<float4*>(ps)      = make_float4(acc0[0], acc0[1], acc0[2], acc0[3]);
        *reinterpret_cast<float4*>(ps + 4)  = make_float4(acc0[4], acc0[5], acc0[6], acc0[7]);
        *reinterpret_cast<float4*>(ps + 8)  = make_float4(acc1[0], acc1[1], acc1[2], acc1[3]);
        *reinterpret_cast<float4*>(ps + 12) = make_float4(acc1[4], acc1[5], acc1[6], acc1[7]);
    }
    __syncthreads();
    if (!cihalf) {
        const float* ps = xs + quad * 1024 + lane * 16;
        float4 o0 = *reinterpret_cast<const float4*>(ps);
        float4 o1 = *reinterpret_cast<const float4*>(ps + 4);
        float4 o2 = *reinterpret_cast<const float4*>(ps + 8);
        float4 o3 = *reinterpret_cast<const float4*>(ps + 12);
        acc0[0] = fmaxf(acc0[0], o0.x); acc0[1] = fmaxf(acc0[1], o0.y);
        acc0[2] = fmaxf(acc0[2], o0.z); acc0[3] = fmaxf(acc0[3], o0.w);
        acc0[4] = fmaxf(acc0[4], o1.x); acc0[5] = fmaxf(acc0[5], o1.y);
        acc0[6] = fmaxf(acc0[6], o1.z); acc0[7] = fmaxf(acc0[7], o1.w);
        acc1[0] = fmaxf(acc1[0], o2.x); acc1[1] = fmaxf(acc1[1], o2.y);
        acc1[2] = fmaxf(acc1[2], o2.z); acc1[3] = fmaxf(acc1[3], o2.w);
        acc1[4] = fmaxf(acc1[4], o3.x); acc1[5] = fmaxf(acc1[5], o3.y);
        acc1[6] = fmaxf(acc1[6], o3.z); acc1[7] = fmaxf(acc1[7], o3.w);

        float* po = out + (((size_t)b * Co + lane) * Hn + h0) * Wn + w0h + woff;
        *reinterpret_cast<float4*>(po)          = make_float4(acc0[0], acc0[1], acc0[2], acc0[3]);
        *reinterpret_cast<float4*>(po + 4)      = make_float4(acc0[4], acc0[5], acc0[6], acc0[7]);
        *reinterpret_cast<float4*>(po + Wn)     = make_float4(acc1[0], acc1[1], acc1[2], acc1[3]);
        *reinterpret_cast<float4*>(po + Wn + 4) = make_float4(acc1[4], acc1[5], acc1[6], acc1[7]);
    }
}

extern "C" void kernel_launch(void* const* d_in, const int* in_sizes, int n_in,
                              void* d_out, int out_size, void* d_ws, size_t ws_size,
                              hipStream_t stream) {
    const float* x  = (const float*)d_in[0];
    const float* wt = (const float*)d_in[1];
    float* out = (float*)d_out;
    float* wT  = (float*)d_ws;   // 147456 B

    wtrans_kernel<<<(WT_ELEMS + 255) / 256, 256, 0, stream>>>(wt, wT);

    // 512 blocks x 512 threads = 2 blocks/CU = 16 waves/CU; LDS 40 KB x 2.
    maxconv_main<<<512, 512, 0, stream>>>(x, wT, out);
}